// Round 4
// baseline (23.670 us; speedup 1.0000x reference)
//
#include <hip/hip_runtime.h>

#define BATCH 16
#define LEN 512
#define HID 384
#define TOUT 3584            // LEN * (DUR_MAX-1) = 512*7
#define VEC (HID / 4)        // 96 float4 per output row
#define TPB 512              // threads per block (= LEN, one elem each for scan)
#define NWAVE (TPB / 64)     // 8 waves
#define T_TILE 64            // output timesteps per block; TOUT/T_TILE = 56

typedef float f32x4 __attribute__((ext_vector_type(4)));

// Fused kernel, per-block (b, 64-timestep tile):
//   phase 1: wave-shuffle inclusive scan of durations[b,:] (2 barriers total)
//   phase 2: binary search for the tile's 64 timesteps -> sidx / mask
//   phase 3: stream 64*96 float4 gathered non-temporal writes (12/thread)
__global__ void __launch_bounds__(TPB)
fused_length_regulator(const f32x4* __restrict__ ehs,
                       const int* __restrict__ dur,
                       f32x4* __restrict__ out,
                       float* __restrict__ mask_out) {
    __shared__ int s[LEN];
    __shared__ int wsum[NWAVE];
    __shared__ int sidx[T_TILE];

    const int b    = blockIdx.y;
    const int tid  = threadIdx.x;
    const int lane = tid & 63;
    const int wid  = tid >> 6;

    // phase 1: inclusive cumsum. Wave-local scan via shuffles, then add
    // prefix of wave sums.
    int v = dur[b * LEN + tid];
    #pragma unroll
    for (int off = 1; off < 64; off <<= 1) {
        int n = __shfl_up(v, off, 64);
        if (lane >= off) v += n;
    }
    if (lane == 63) wsum[wid] = v;
    __syncthreads();
    int add = 0;
    #pragma unroll
    for (int w = 0; w < NWAVE; ++w)
        if (w < wid) add += wsum[w];
    v += add;
    s[tid] = v;
    __syncthreads();

    // phase 2: searchsorted(cs, t, side='right') for this block's 64 t's
    const int t0 = blockIdx.x * T_TILE;
    if (tid < T_TILE) {
        const int t = t0 + tid;
        const int total = s[LEN - 1];
        int lo = 0, hi = LEN;
        while (lo < hi) {
            int mid = (lo + hi) >> 1;
            if (s[mid] <= t) lo = mid + 1; else hi = mid;
        }
        int idx = lo < (LEN - 1) ? lo : (LEN - 1);
        const bool m = t < total;
        sidx[tid] = m ? idx : -1;
        __builtin_nontemporal_store(m ? 1.0f : 0.0f, &mask_out[b * TOUT + t]);
    }
    __syncthreads();

    // phase 3: gathered streaming copy, 64 rows x 96 float4 = 6144 float4.
    // Non-temporal stores: output is write-once streaming; keep L2 for the
    // source rows (reused ~7x on average).
    const f32x4* __restrict__ src_b = ehs + (long long)b * LEN * VEC;
    f32x4* __restrict__ dst = out + ((long long)b * TOUT + t0) * VEC;
    #pragma unroll
    for (int it = 0; it < (T_TILE * VEC) / TPB; ++it) {   // 12 iterations
        const int j = it * TPB + tid;
        const int r = j / VEC;            // magic-mul, cheap
        const int c = j - r * VEC;
        const int iv = sidx[r];
        f32x4 val = (f32x4)(0.f);
        if (iv >= 0) val = src_b[iv * VEC + c];
        __builtin_nontemporal_store(val, &dst[j]);
    }
}

extern "C" void kernel_launch(void* const* d_in, const int* in_sizes, int n_in,
                              void* d_out, int out_size, void* d_ws, size_t ws_size,
                              hipStream_t stream) {
    const float* ehs = (const float*)d_in[0];
    const int* dur   = (const int*)d_in[1];
    // d_in[2] = max_durations scalar; compile-time constant TOUT used.

    float* out_expanded = (float*)d_out;                                  // [B,T,H]
    float* out_mask     = (float*)d_out + (long long)BATCH * TOUT * HID;  // [B,T]

    dim3 grid(TOUT / T_TILE, BATCH);   // 56 x 16 = 896 blocks
    fused_length_regulator<<<grid, TPB, 0, stream>>>(
        (const f32x4*)ehs, dur, (f32x4*)out_expanded, out_mask);
}

// Round 5
// 21.141 us; speedup vs baseline: 1.1196x; 1.1196x over previous
//
#include <hip/hip_runtime.h>

#define BATCH 16
#define LEN 512
#define HID 384
#define TOUT 3584            // LEN * (DUR_MAX-1) = 512*7
#define VEC (HID / 4)        // 96 float4 per output row
#define TPB 512              // threads per block (= LEN, one elem each for scan)
#define NWAVE (TPB / 64)     // 8 waves
#define T_TILE 64            // output timesteps per block; TOUT/T_TILE = 56

typedef float f32x4 __attribute__((ext_vector_type(4)));

// Fused kernel, per-block (b, 64-timestep tile):
//   phase 1: wave-shuffle inclusive scan of durations[b,:] (2 barriers total)
//   phase 2: binary search for the tile's 64 timesteps -> sidx / mask
//   phase 3: stream 64*96 float4 gathered writes (12/thread, plain stores —
//            NT stores measured -10% in R4: they bypass L2 write buffering)
__global__ void __launch_bounds__(TPB)
fused_length_regulator(const f32x4* __restrict__ ehs,
                       const int* __restrict__ dur,
                       f32x4* __restrict__ out,
                       float* __restrict__ mask_out) {
    __shared__ int s[LEN];
    __shared__ int wsum[NWAVE];
    __shared__ int sidx[T_TILE];

    const int b    = blockIdx.y;
    const int tid  = threadIdx.x;
    const int lane = tid & 63;
    const int wid  = tid >> 6;

    // phase 1: inclusive cumsum. Wave-local scan via shuffles, then add
    // prefix of wave sums.
    int v = dur[b * LEN + tid];
    #pragma unroll
    for (int off = 1; off < 64; off <<= 1) {
        int n = __shfl_up(v, off, 64);
        if (lane >= off) v += n;
    }
    if (lane == 63) wsum[wid] = v;
    __syncthreads();
    int add = 0;
    #pragma unroll
    for (int w = 0; w < NWAVE; ++w)
        if (w < wid) add += wsum[w];
    v += add;
    s[tid] = v;
    __syncthreads();

    // phase 2: searchsorted(cs, t, side='right') for this block's 64 t's
    const int t0 = blockIdx.x * T_TILE;
    if (tid < T_TILE) {
        const int t = t0 + tid;
        const int total = s[LEN - 1];
        int lo = 0, hi = LEN;
        while (lo < hi) {
            int mid = (lo + hi) >> 1;
            if (s[mid] <= t) lo = mid + 1; else hi = mid;
        }
        int idx = lo < (LEN - 1) ? lo : (LEN - 1);
        const bool m = t < total;
        sidx[tid] = m ? idx : -1;
        mask_out[b * TOUT + t] = m ? 1.0f : 0.0f;
    }
    __syncthreads();

    // phase 3: gathered streaming copy, 64 rows x 96 float4 = 6144 float4.
    const f32x4* __restrict__ src_b = ehs + (long long)b * LEN * VEC;
    f32x4* __restrict__ dst = out + ((long long)b * TOUT + t0) * VEC;
    #pragma unroll
    for (int it = 0; it < (T_TILE * VEC) / TPB; ++it) {   // 12 iterations
        const int j = it * TPB + tid;
        const int r = j / VEC;            // magic-mul, cheap
        const int c = j - r * VEC;
        const int iv = sidx[r];
        f32x4 val = (f32x4)(0.f);
        if (iv >= 0) val = src_b[iv * VEC + c];
        dst[j] = val;
    }
}

extern "C" void kernel_launch(void* const* d_in, const int* in_sizes, int n_in,
                              void* d_out, int out_size, void* d_ws, size_t ws_size,
                              hipStream_t stream) {
    const float* ehs = (const float*)d_in[0];
    const int* dur   = (const int*)d_in[1];
    // d_in[2] = max_durations scalar; compile-time constant TOUT used.

    float* out_expanded = (float*)d_out;                                  // [B,T,H]
    float* out_mask     = (float*)d_out + (long long)BATCH * TOUT * HID;  // [B,T]

    dim3 grid(TOUT / T_TILE, BATCH);   // 56 x 16 = 896 blocks
    fused_length_regulator<<<grid, TPB, 0, stream>>>(
        (const f32x4*)ehs, dur, (f32x4*)out_expanded, out_mask);
}

// Round 6
// 21.121 us; speedup vs baseline: 1.1207x; 1.0010x over previous
//
#include <hip/hip_runtime.h>

#define BATCH 16
#define LEN 512
#define HID 384
#define TOUT 3584            // LEN * (DUR_MAX-1) = 512*7
#define VEC (HID / 4)        // 96 float4 per output row
#define TPB 512              // threads per block (= LEN, one elem each for scan)
#define NWAVE (TPB / 64)     // 8 waves
#define T_TILE 128           // output timesteps per block; TOUT/T_TILE = 28

typedef float f32x4 __attribute__((ext_vector_type(4)));

// Fused kernel, per-block (b, 128-timestep tile):
//   phase 1: wave-shuffle inclusive scan of durations[b,:] (2 barriers total)
//   phase 2: binary search for the tile's 128 timesteps -> sidx / mask
//   phase 3: stream 128*96 float4 gathered writes (24/thread, plain stores —
//            NT stores measured -10% in R4: they bypass L2 write buffering)
__global__ void __launch_bounds__(TPB)
fused_length_regulator(const f32x4* __restrict__ ehs,
                       const int* __restrict__ dur,
                       f32x4* __restrict__ out,
                       float* __restrict__ mask_out) {
    __shared__ int s[LEN];
    __shared__ int wsum[NWAVE];
    __shared__ int sidx[T_TILE];

    const int b    = blockIdx.y;
    const int tid  = threadIdx.x;
    const int lane = tid & 63;
    const int wid  = tid >> 6;

    // phase 1: inclusive cumsum. Wave-local scan via shuffles, then add
    // prefix of wave sums.
    int v = dur[b * LEN + tid];
    #pragma unroll
    for (int off = 1; off < 64; off <<= 1) {
        int n = __shfl_up(v, off, 64);
        if (lane >= off) v += n;
    }
    if (lane == 63) wsum[wid] = v;
    __syncthreads();
    int add = 0;
    #pragma unroll
    for (int w = 0; w < NWAVE; ++w)
        if (w < wid) add += wsum[w];
    v += add;
    s[tid] = v;
    __syncthreads();

    // phase 2: searchsorted(cs, t, side='right') for this block's 128 t's
    const int t0 = blockIdx.x * T_TILE;
    if (tid < T_TILE) {
        const int t = t0 + tid;
        const int total = s[LEN - 1];
        int lo = 0, hi = LEN;
        while (lo < hi) {
            int mid = (lo + hi) >> 1;
            if (s[mid] <= t) lo = mid + 1; else hi = mid;
        }
        int idx = lo < (LEN - 1) ? lo : (LEN - 1);
        const bool m = t < total;
        sidx[tid] = m ? idx : -1;
        mask_out[b * TOUT + t] = m ? 1.0f : 0.0f;
    }
    __syncthreads();

    // phase 3: gathered streaming copy, 128 rows x 96 float4 = 12288 float4.
    const f32x4* __restrict__ src_b = ehs + (long long)b * LEN * VEC;
    f32x4* __restrict__ dst = out + ((long long)b * TOUT + t0) * VEC;
    #pragma unroll
    for (int it = 0; it < (T_TILE * VEC) / TPB; ++it) {   // 24 iterations
        const int j = it * TPB + tid;
        const int r = j / VEC;            // magic-mul, cheap
        const int c = j - r * VEC;
        const int iv = sidx[r];
        f32x4 val = (f32x4)(0.f);
        if (iv >= 0) val = src_b[iv * VEC + c];
        dst[j] = val;
    }
}

extern "C" void kernel_launch(void* const* d_in, const int* in_sizes, int n_in,
                              void* d_out, int out_size, void* d_ws, size_t ws_size,
                              hipStream_t stream) {
    const float* ehs = (const float*)d_in[0];
    const int* dur   = (const int*)d_in[1];
    // d_in[2] = max_durations scalar; compile-time constant TOUT used.

    float* out_expanded = (float*)d_out;                                  // [B,T,H]
    float* out_mask     = (float*)d_out + (long long)BATCH * TOUT * HID;  // [B,T]

    dim3 grid(TOUT / T_TILE, BATCH);   // 28 x 16 = 448 blocks
    fused_length_regulator<<<grid, TPB, 0, stream>>>(
        (const f32x4*)ehs, dur, (f32x4*)out_expanded, out_mask);
}

// Round 7
// 20.842 us; speedup vs baseline: 1.1357x; 1.0134x over previous
//
#include <hip/hip_runtime.h>

#define BATCH 16
#define LEN 512
#define HID 384
#define TOUT 3584            // LEN * (DUR_MAX-1) = 512*7
#define VEC (HID / 4)        // 96 float4 per output row
#define TPB 512              // threads per block (= LEN, one elem each for scan)
#define NWAVE (TPB / 64)     // 8 waves
#define T_TILE 112           // output timesteps per block; TOUT/T_TILE = 32
                             // -> grid = 32*16 = 512 blocks = exactly 2/CU

typedef float f32x4 __attribute__((ext_vector_type(4)));

// Fused kernel, per-block (b, 112-timestep tile):
//   phase 1: wave-shuffle inclusive scan of durations[b,:] (2 barriers total)
//   phase 2: binary search for the tile's 112 timesteps -> sidx / mask
//   phase 3: stream 112*96 float4 gathered writes (21/thread, plain stores —
//            NT stores measured -10% in R4: they bypass L2 write buffering)
__global__ void __launch_bounds__(TPB)
fused_length_regulator(const f32x4* __restrict__ ehs,
                       const int* __restrict__ dur,
                       f32x4* __restrict__ out,
                       float* __restrict__ mask_out) {
    __shared__ int s[LEN];
    __shared__ int wsum[NWAVE];
    __shared__ int sidx[T_TILE];

    const int b    = blockIdx.y;
    const int tid  = threadIdx.x;
    const int lane = tid & 63;
    const int wid  = tid >> 6;

    // phase 1: inclusive cumsum. Wave-local scan via shuffles, then add
    // prefix of wave sums.
    int v = dur[b * LEN + tid];
    #pragma unroll
    for (int off = 1; off < 64; off <<= 1) {
        int n = __shfl_up(v, off, 64);
        if (lane >= off) v += n;
    }
    if (lane == 63) wsum[wid] = v;
    __syncthreads();
    int add = 0;
    #pragma unroll
    for (int w = 0; w < NWAVE; ++w)
        if (w < wid) add += wsum[w];
    v += add;
    s[tid] = v;
    __syncthreads();

    // phase 2: searchsorted(cs, t, side='right') for this block's 112 t's
    const int t0 = blockIdx.x * T_TILE;
    if (tid < T_TILE) {
        const int t = t0 + tid;
        const int total = s[LEN - 1];
        int lo = 0, hi = LEN;
        while (lo < hi) {
            int mid = (lo + hi) >> 1;
            if (s[mid] <= t) lo = mid + 1; else hi = mid;
        }
        int idx = lo < (LEN - 1) ? lo : (LEN - 1);
        const bool m = t < total;
        sidx[tid] = m ? idx : -1;
        mask_out[b * TOUT + t] = m ? 1.0f : 0.0f;
    }
    __syncthreads();

    // phase 3: gathered streaming copy, 112 rows x 96 float4 = 10752 float4.
    const f32x4* __restrict__ src_b = ehs + (long long)b * LEN * VEC;
    f32x4* __restrict__ dst = out + ((long long)b * TOUT + t0) * VEC;
    #pragma unroll
    for (int it = 0; it < (T_TILE * VEC) / TPB; ++it) {   // 21 iterations
        const int j = it * TPB + tid;
        const int r = j / VEC;            // magic-mul, cheap
        const int c = j - r * VEC;
        const int iv = sidx[r];
        f32x4 val = (f32x4)(0.f);
        if (iv >= 0) val = src_b[iv * VEC + c];
        dst[j] = val;
    }
}

extern "C" void kernel_launch(void* const* d_in, const int* in_sizes, int n_in,
                              void* d_out, int out_size, void* d_ws, size_t ws_size,
                              hipStream_t stream) {
    const float* ehs = (const float*)d_in[0];
    const int* dur   = (const int*)d_in[1];
    // d_in[2] = max_durations scalar; compile-time constant TOUT used.

    float* out_expanded = (float*)d_out;                                  // [B,T,H]
    float* out_mask     = (float*)d_out + (long long)BATCH * TOUT * HID;  // [B,T]

    dim3 grid(TOUT / T_TILE, BATCH);   // 32 x 16 = 512 blocks, 2 per CU
    fused_length_regulator<<<grid, TPB, 0, stream>>>(
        (const f32x4*)ehs, dur, (f32x4*)out_expanded, out_mask);
}